// Round 1
// baseline (198.011 us; speedup 1.0000x reference)
//
#include <hip/hip_runtime.h>
#include <math.h>

#define NR   2048   // rows
#define XD   512    // x/y dim
#define HID  300
#define BS   256    // batch chunk
#define NCH  8      // chunks

#define TM 64
#define TN 64
#define TK 32

__device__ __forceinline__ float softplus_f(float x) {
    return fmaxf(x, 0.f) + log1pf(__expf(-fabsf(x)));
}

// id 0: LPt = (nl @ W1l)^T            -> [HID][NR]
// id 1: GPB = ng @ W1g + b1           -> [NR][HID]
// id 2: P0  = pl @ W1l + pg @ W1g + b1-> [NR][HID]   (K=1024 concat)
__global__ __launch_bounds__(256) void gemm3(
    const float* __restrict__ pl, const float* __restrict__ pg,
    const float* __restrict__ nl, const float* __restrict__ ng,
    const float* __restrict__ W1, const float* __restrict__ b1,
    float* __restrict__ LPt, float* __restrict__ GPB, float* __restrict__ P0)
{
    __shared__ float As[TK][TM + 4];
    __shared__ float Ws[TK][TN + 4];
    const int id = blockIdx.z;
    const int m0 = blockIdx.x * TM;
    const int n0 = blockIdx.y * TN;
    const int tid = threadIdx.x;
    const int tx = tid & 15, ty = tid >> 4;
    const int K = (id == 2) ? 2 * XD : XD;

    float acc[4][4] = {};

    for (int k0 = 0; k0 < K; k0 += TK) {
        const float* Ab;
        int kofs;
        if (id == 0)      { Ab = nl; kofs = k0; }
        else if (id == 1) { Ab = ng; kofs = k0; }
        else if (k0 < XD) { Ab = pl; kofs = k0; }
        else              { Ab = pg; kofs = k0 - XD; }
        const int wr0 = (id == 1) ? XD + k0 : k0;  // W1 row base for this k-tile

        #pragma unroll
        for (int r = 0; r < 8; ++r) {
            const int e = tid + 256 * r;
            const int m = e >> 5, kk = e & 31;
            As[kk][m] = Ab[(m0 + m) * XD + kofs + kk];
        }
        #pragma unroll
        for (int r = 0; r < 8; ++r) {
            const int e = tid + 256 * r;
            const int kk = e >> 6, n = e & 63;
            Ws[kk][n] = (n0 + n < HID) ? W1[(wr0 + kk) * HID + n0 + n] : 0.f;
        }
        __syncthreads();

        #pragma unroll
        for (int kk = 0; kk < TK; ++kk) {
            const float4 a4 = *(const float4*)&As[kk][ty * 4];
            const float4 b4 = *(const float4*)&Ws[kk][tx * 4];
            const float av[4] = {a4.x, a4.y, a4.z, a4.w};
            const float bv[4] = {b4.x, b4.y, b4.z, b4.w};
            #pragma unroll
            for (int i = 0; i < 4; ++i)
                #pragma unroll
                for (int j = 0; j < 4; ++j)
                    acc[i][j] = fmaf(av[i], bv[j], acc[i][j]);
        }
        __syncthreads();
    }

    #pragma unroll
    for (int i = 0; i < 4; ++i) {
        const int m = m0 + ty * 4 + i;
        #pragma unroll
        for (int j = 0; j < 4; ++j) {
            const int n = n0 + tx * 4 + j;
            if (n < HID) {
                if (id == 0)      LPt[n * NR + m]  = acc[i][j];
                else if (id == 1) GPB[m * HID + n] = acc[i][j] + b1[n];
                else              P0[m * HID + n]  = acc[i][j] + b1[n];
            }
        }
    }
}

// block = (chunk, group of 4 g rows); thread = one l (0..255)
__global__ __launch_bounds__(256) void neg_fused(
    const float* __restrict__ LPt, const float* __restrict__ GPB,
    const float* __restrict__ W2, const float* __restrict__ b2,
    float* __restrict__ negp)
{
    __shared__ float gbs[4][HID];
    __shared__ float w2s[HID];
    __shared__ float red[4];
    const int chunk = blockIdx.y;
    const int g0 = blockIdx.x * 4;
    const int tid = threadIdx.x;

    for (int idx = tid; idx < 4 * HID; idx += 256) {
        const int gt = idx / HID, k = idx - gt * HID;
        gbs[gt][k] = GPB[(chunk * BS + g0 + gt) * HID + k];
    }
    for (int idx = tid; idx < HID; idx += 256) w2s[idx] = W2[idx];
    __syncthreads();

    const int lg = chunk * BS + tid;
    float acc[4] = {0.f, 0.f, 0.f, 0.f};
    for (int k = 0; k < HID; k += 4) {
        const float4 w4 = *(const float4*)&w2s[k];
        const float lp0 = LPt[(k + 0) * NR + lg];
        const float lp1 = LPt[(k + 1) * NR + lg];
        const float lp2 = LPt[(k + 2) * NR + lg];
        const float lp3 = LPt[(k + 3) * NR + lg];
        #pragma unroll
        for (int gt = 0; gt < 4; ++gt) {
            const float4 g4 = *(const float4*)&gbs[gt][k];
            acc[gt] = fmaf(fmaxf(g4.x + lp0, 0.f), w4.x, acc[gt]);
            acc[gt] = fmaf(fmaxf(g4.y + lp1, 0.f), w4.y, acc[gt]);
            acc[gt] = fmaf(fmaxf(g4.z + lp2, 0.f), w4.z, acc[gt]);
            acc[gt] = fmaf(fmaxf(g4.w + lp3, 0.f), w4.w, acc[gt]);
        }
    }

    const float b2v = b2[0];
    float lse_sum = 0.f;
    #pragma unroll
    for (int gt = 0; gt < 4; ++gt) {
        const float s = softplus_f(acc[gt] + b2v);
        float m = s;
        #pragma unroll
        for (int o = 32; o > 0; o >>= 1) m = fmaxf(m, __shfl_xor(m, o));
        if ((tid & 63) == 0) red[tid >> 6] = m;
        __syncthreads();
        m = fmaxf(fmaxf(red[0], red[1]), fmaxf(red[2], red[3]));
        __syncthreads();
        float e = __expf(s - m);
        #pragma unroll
        for (int o = 32; o > 0; o >>= 1) e += __shfl_xor(e, o);
        if ((tid & 63) == 0) red[tid >> 6] = e;
        __syncthreads();
        const float sum = red[0] + red[1] + red[2] + red[3];
        __syncthreads();
        lse_sum += m + __logf(sum);
    }
    if (tid == 0) negp[blockIdx.y * 64 + blockIdx.x] = lse_sum;
}

__global__ __launch_bounds__(256) void pos_term(
    const float* __restrict__ P0, const float* __restrict__ W2,
    const float* __restrict__ b2, float* __restrict__ posp)
{
    const int tid = threadIdx.x;
    const int i = blockIdx.x * 256 + tid;
    const float4* row = (const float4*)(P0 + i * HID);
    const float4* w = (const float4*)W2;
    float acc = 0.f;
    for (int q = 0; q < HID / 4; ++q) {
        const float4 p = row[q];
        const float4 wv = w[q];
        acc += fmaxf(p.x, 0.f) * wv.x + fmaxf(p.y, 0.f) * wv.y
             + fmaxf(p.z, 0.f) * wv.z + fmaxf(p.w, 0.f) * wv.w;
    }
    float sp = softplus_f(acc + b2[0]);
    #pragma unroll
    for (int o = 32; o > 0; o >>= 1) sp += __shfl_xor(sp, o);
    __shared__ float red[4];
    if ((tid & 63) == 0) red[tid >> 6] = sp;
    __syncthreads();
    if (tid == 0) posp[blockIdx.x] = red[0] + red[1] + red[2] + red[3];
}

__global__ __launch_bounds__(256) void finalize(
    const float* __restrict__ negp, const float* __restrict__ posp,
    float* __restrict__ out)
{
    const int tid = threadIdx.x;
    float v = negp[tid] + negp[tid + 256];
    if (tid < 8) v -= posp[tid];
    #pragma unroll
    for (int o = 32; o > 0; o >>= 1) v += __shfl_xor(v, o);
    __shared__ float red[4];
    if ((tid & 63) == 0) red[tid >> 6] = v;
    __syncthreads();
    if (tid == 0) out[0] = (red[0] + red[1] + red[2] + red[3]) * (1.f / 2048.f);
}

extern "C" void kernel_launch(void* const* d_in, const int* in_sizes, int n_in,
                              void* d_out, int out_size, void* d_ws, size_t ws_size,
                              hipStream_t stream)
{
    const float* pl = (const float*)d_in[0];
    const float* pg = (const float*)d_in[1];
    const float* nl = (const float*)d_in[2];
    const float* ng = (const float*)d_in[3];
    const float* W1 = (const float*)d_in[4];
    const float* b1 = (const float*)d_in[5];
    const float* W2 = (const float*)d_in[6];
    const float* b2 = (const float*)d_in[7];

    float* ws   = (float*)d_ws;
    float* LPt  = ws;                  // 300*2048
    float* GPB  = ws + 614400;         // 2048*300
    float* P0   = ws + 2 * 614400;     // 2048*300
    float* negp = ws + 3 * 614400;     // 512
    float* posp = negp + 512;          // 8
    float* out  = (float*)d_out;

    hipLaunchKernelGGL(gemm3, dim3(NR / TM, 5, 3), dim3(256), 0, stream,
                       pl, pg, nl, ng, W1, b1, LPt, GPB, P0);
    hipLaunchKernelGGL(neg_fused, dim3(64, NCH), dim3(256), 0, stream,
                       LPt, GPB, W2, b2, negp);
    hipLaunchKernelGGL(pos_term, dim3(NR / 256), dim3(256), 0, stream,
                       P0, W2, b2, posp);
    hipLaunchKernelGGL(finalize, dim3(1), dim3(256), 0, stream,
                       negp, posp, out);
}

// Round 2
// 79.652 us; speedup vs baseline: 2.4859x; 2.4859x over previous
//
#include <hip/hip_runtime.h>
#include <math.h>

#define NR   2048
#define XD   512
#define HID  300
#define BS   256
#define NCH  8
#define NPAD 320          // HID padded to 32
#define KTOT 1024
#define GSTR 304          // row stride for GPB/P0 (float4-aligned)

typedef __attribute__((ext_vector_type(8))) short bf16x8;
typedef __attribute__((ext_vector_type(4))) float f32x4;

__device__ __forceinline__ float softplus_f(float x) {
    return fmaxf(x, 0.f) + log1pf(__expf(-fabsf(x)));
}
__device__ __forceinline__ unsigned short f2bf(float f) {
    unsigned int u = __float_as_uint(f);
    u += 0x7FFFu + ((u >> 16) & 1u);   // RNE
    return (unsigned short)(u >> 16);
}

// grid.x = 2048 (Aneg rows) + 2048 (Apos rows) + 320 (Wt tiles)
__global__ __launch_bounds__(256) void convert(
    const float* __restrict__ pl, const float* __restrict__ pg,
    const float* __restrict__ nl, const float* __restrict__ ng,
    const float* __restrict__ W1,
    unsigned short* __restrict__ Aneg, unsigned short* __restrict__ Apos,
    unsigned short* __restrict__ Wt)
{
    const int b = blockIdx.x, tid = threadIdx.x;
    if (b < 4096) {
        const int m = (b < 2048) ? b : b - 2048;
        const float* lo = (b < 2048) ? nl : pl;
        const float* hi = (b < 2048) ? ng : pg;
        unsigned short* dst = (b < 2048) ? Aneg : Apos;
        const int kq = tid * 4;
        const float4 v = (kq < XD) ? *(const float4*)(lo + m * XD + kq)
                                   : *(const float4*)(hi + m * XD + kq - XD);
        ushort4 o;
        o.x = f2bf(v.x); o.y = f2bf(v.y); o.z = f2bf(v.z); o.w = f2bf(v.w);
        *(ushort4*)(dst + m * KTOT + kq) = o;
    } else {
        // W1 [1024][300] -> Wt [320][1024] bf16, zero-padded rows 300..319
        __shared__ unsigned short ts[16][72];
        const int t = b - 4096;
        const int nt = t % 20, kt = t / 20;   // 20 n-tiles x 16 k-tiles
        const int n = nt * 16 + (tid & 15);
        const int kl = tid >> 4;
        #pragma unroll
        for (int j = 0; j < 4; ++j) {
            const int k = kt * 64 + kl * 4 + j;
            const float val = (n < HID) ? W1[k * HID + n] : 0.f;
            ts[tid & 15][kl * 4 + j] = f2bf(val);
        }
        __syncthreads();
        const int nw = tid >> 4, kw = (tid & 15) * 4;
        ushort4 o;
        o.x = ts[nw][kw]; o.y = ts[nw][kw + 1]; o.z = ts[nw][kw + 2]; o.w = ts[nw][kw + 3];
        *(ushort4*)(Wt + (nt * 16 + nw) * KTOT + kt * 64 + kw) = o;
    }
}

// One wave per block, 32x32 tile of 16x16x32 MFMAs.
// job 0: LP4 (nl @ W1l, k<512)    job 1: GPB (ng @ W1g + b1, k>=512)
// job 2: P0  ([pl|pg] @ W1 + b1, K=1024)
__global__ __launch_bounds__(64) void mfma_gemm(
    const unsigned short* __restrict__ Aneg, const unsigned short* __restrict__ Apos,
    const unsigned short* __restrict__ Wt, const float* __restrict__ b1,
    float* __restrict__ LP4, float* __restrict__ GPB, float* __restrict__ P0)
{
    const int job = blockIdx.z;
    const int m0 = blockIdx.x * 32, n0 = blockIdx.y * 32;
    const int lane = threadIdx.x;
    const int r = lane & 15, g = lane >> 4;

    const unsigned short* A = (job == 2) ? Apos : Aneg;
    const int kbeg = (job == 1) ? XD : 0;
    const int klen = (job == 0 || job == 1) ? XD : KTOT;

    const unsigned short* a0p = A  + (m0 + r) * KTOT + kbeg + 8 * g;
    const unsigned short* a1p = a0p + 16 * KTOT;
    const unsigned short* b0p = Wt + (n0 + r) * KTOT + kbeg + 8 * g;
    const unsigned short* b1p = b0p + 16 * KTOT;

    f32x4 acc00 = {0,0,0,0}, acc01 = {0,0,0,0}, acc10 = {0,0,0,0}, acc11 = {0,0,0,0};

    #pragma unroll 8
    for (int k = 0; k < klen; k += 32) {
        const bf16x8 a0 = *(const bf16x8*)(a0p + k);
        const bf16x8 a1 = *(const bf16x8*)(a1p + k);
        const bf16x8 w0 = *(const bf16x8*)(b0p + k);
        const bf16x8 w1 = *(const bf16x8*)(b1p + k);
        acc00 = __builtin_amdgcn_mfma_f32_16x16x32_bf16(a0, w0, acc00, 0, 0, 0);
        acc01 = __builtin_amdgcn_mfma_f32_16x16x32_bf16(a0, w1, acc01, 0, 0, 0);
        acc10 = __builtin_amdgcn_mfma_f32_16x16x32_bf16(a1, w0, acc10, 0, 0, 0);
        acc11 = __builtin_amdgcn_mfma_f32_16x16x32_bf16(a1, w1, acc11, 0, 0, 0);
    }

    // D layout: row = 4*g + j (+16*mi), col = r (+16*ni)
    f32x4 accs[2][2] = {{acc00, acc01}, {acc10, acc11}};
    #pragma unroll
    for (int mi = 0; mi < 2; ++mi) {
        #pragma unroll
        for (int ni = 0; ni < 2; ++ni) {
            const int n = n0 + ni * 16 + r;
            const int mb = m0 + mi * 16 + 4 * g;
            const f32x4 v = accs[mi][ni];
            if (job == 0) {
                float* base = LP4 + ((size_t)(n >> 2) * NR + mb) * 4 + (n & 3);
                base[0] = v[0]; base[4] = v[1]; base[8] = v[2]; base[12] = v[3];
            } else if (n < HID) {
                const float bias = b1[n];
                float* out = (job == 1) ? GPB : P0;
                #pragma unroll
                for (int j = 0; j < 4; ++j)
                    out[(size_t)(mb + j) * GSTR + n] = v[j] + bias;
            }
        }
    }
}

// block = (g-group of 4, chunk); thread = one l (0..255)
__global__ __launch_bounds__(256) void neg_fused(
    const float* __restrict__ LP4, const float* __restrict__ GPB,
    const float* __restrict__ W2, const float* __restrict__ b2,
    float* __restrict__ negp)
{
    __shared__ float gbs[4][HID];
    __shared__ float w2s[HID];
    __shared__ float red[4];
    const int chunk = blockIdx.y;
    const int g0 = blockIdx.x * 4;
    const int tid = threadIdx.x;

    for (int idx = tid; idx < 4 * HID; idx += 256) {
        const int gt = idx / HID, k = idx - gt * HID;
        gbs[gt][k] = GPB[(size_t)(chunk * BS + g0 + gt) * GSTR + k];
    }
    for (int idx = tid; idx < HID; idx += 256) w2s[idx] = W2[idx];
    __syncthreads();

    const int lg = chunk * BS + tid;
    const float4* lp4 = (const float4*)LP4 + lg;
    float acc[4] = {0.f, 0.f, 0.f, 0.f};
    for (int k4 = 0; k4 < HID / 4; ++k4) {
        const float4 lp = lp4[(size_t)k4 * NR];
        const float4 w4 = *(const float4*)&w2s[k4 * 4];
        #pragma unroll
        for (int gt = 0; gt < 4; ++gt) {
            const float4 g4 = *(const float4*)&gbs[gt][k4 * 4];
            acc[gt] = fmaf(fmaxf(g4.x + lp.x, 0.f), w4.x, acc[gt]);
            acc[gt] = fmaf(fmaxf(g4.y + lp.y, 0.f), w4.y, acc[gt]);
            acc[gt] = fmaf(fmaxf(g4.z + lp.z, 0.f), w4.z, acc[gt]);
            acc[gt] = fmaf(fmaxf(g4.w + lp.w, 0.f), w4.w, acc[gt]);
        }
    }

    const float b2v = b2[0];
    float lse_sum = 0.f;
    #pragma unroll
    for (int gt = 0; gt < 4; ++gt) {
        const float s = softplus_f(acc[gt] + b2v);
        float m = s;
        #pragma unroll
        for (int o = 32; o > 0; o >>= 1) m = fmaxf(m, __shfl_xor(m, o));
        if ((tid & 63) == 0) red[tid >> 6] = m;
        __syncthreads();
        m = fmaxf(fmaxf(red[0], red[1]), fmaxf(red[2], red[3]));
        __syncthreads();
        float e = __expf(s - m);
        #pragma unroll
        for (int o = 32; o > 0; o >>= 1) e += __shfl_xor(e, o);
        if ((tid & 63) == 0) red[tid >> 6] = e;
        __syncthreads();
        const float sum = red[0] + red[1] + red[2] + red[3];
        __syncthreads();
        lse_sum += m + __logf(sum);
    }
    if (tid == 0) negp[chunk * 64 + blockIdx.x] = lse_sum;
}

__global__ __launch_bounds__(256) void pos_term(
    const float* __restrict__ P0, const float* __restrict__ W2,
    const float* __restrict__ b2, float* __restrict__ posp)
{
    const int tid = threadIdx.x;
    const int i = blockIdx.x * 256 + tid;
    const float4* row = (const float4*)(P0 + (size_t)i * GSTR);
    const float4* w = (const float4*)W2;
    float acc = 0.f;
    for (int q = 0; q < HID / 4; ++q) {
        const float4 p = row[q];
        const float4 wv = w[q];
        acc += fmaxf(p.x, 0.f) * wv.x + fmaxf(p.y, 0.f) * wv.y
             + fmaxf(p.z, 0.f) * wv.z + fmaxf(p.w, 0.f) * wv.w;
    }
    float sp = softplus_f(acc + b2[0]);
    #pragma unroll
    for (int o = 32; o > 0; o >>= 1) sp += __shfl_xor(sp, o);
    __shared__ float red[4];
    if ((tid & 63) == 0) red[tid >> 6] = sp;
    __syncthreads();
    if (tid == 0) posp[blockIdx.x] = red[0] + red[1] + red[2] + red[3];
}

__global__ __launch_bounds__(256) void finalize(
    const float* __restrict__ negp, const float* __restrict__ posp,
    float* __restrict__ out)
{
    const int tid = threadIdx.x;
    float v = negp[tid] + negp[tid + 256];
    if (tid < 8) v -= posp[tid];
    #pragma unroll
    for (int o = 32; o > 0; o >>= 1) v += __shfl_xor(v, o);
    __shared__ float red[4];
    if ((tid & 63) == 0) red[tid >> 6] = v;
    __syncthreads();
    if (tid == 0) out[0] = (red[0] + red[1] + red[2] + red[3]) * (1.f / 2048.f);
}

extern "C" void kernel_launch(void* const* d_in, const int* in_sizes, int n_in,
                              void* d_out, int out_size, void* d_ws, size_t ws_size,
                              hipStream_t stream)
{
    const float* pl = (const float*)d_in[0];
    const float* pg = (const float*)d_in[1];
    const float* nl = (const float*)d_in[2];
    const float* ng = (const float*)d_in[3];
    const float* W1 = (const float*)d_in[4];
    const float* b1 = (const float*)d_in[5];
    const float* W2 = (const float*)d_in[6];
    const float* b2 = (const float*)d_in[7];

    char* ws = (char*)d_ws;
    unsigned short* Aneg = (unsigned short*)(ws);                       // 4 MB
    unsigned short* Apos = (unsigned short*)(ws + (4u << 20));          // 4 MB
    unsigned short* Wt   = (unsigned short*)(ws + (8u << 20));          // 640 KB
    float* LP4  = (float*)(ws + (9u << 20));                            // 80*2048*16B = 2.62 MB
    float* GPB  = (float*)(ws + (12u << 20));                           // 2048*304*4 = 2.49 MB
    float* P0   = (float*)(ws + (15u << 20));                           // 2.49 MB
    float* negp = (float*)(ws + (18u << 20));                           // 512 f
    float* posp = negp + 512;
    float* out  = (float*)d_out;

    hipLaunchKernelGGL(convert, dim3(4096 + 320), dim3(256), 0, stream,
                       pl, pg, nl, ng, W1, Aneg, Apos, Wt);
    hipLaunchKernelGGL(mfma_gemm, dim3(NR / 32, NPAD / 32, 3), dim3(64), 0, stream,
                       Aneg, Apos, Wt, b1, LP4, GPB, P0);
    hipLaunchKernelGGL(neg_fused, dim3(64, NCH), dim3(256), 0, stream,
                       LP4, GPB, W2, b2, negp);
    hipLaunchKernelGGL(pos_term, dim3(NR / 256), dim3(256), 0, stream,
                       P0, W2, b2, posp);
    hipLaunchKernelGGL(finalize, dim3(1), dim3(256), 0, stream,
                       negp, posp, out);
}